// Round 2
// baseline (283.090 us; speedup 1.0000x reference)
//
#include <hip/hip_runtime.h>
#include <math.h>
#include <limits.h>

// RelativeBucketedTimeAndPositionBasedBias — B=16, N=2048, NUM_BUCKETS=128
// out[b,i,j] = pos_w[N-1 + j - i] + ts_w[bucket(b,i,j)]
//   diff = ext[b,i+1] - ext[b,j]; m = max(|diff·causal|, 1)  (integer, < 2^24)
//
// VERIFIED BIT-EXACT (R12-R14, absmax=0): ref pipeline is
//   bucket = clip(trunc( RN_f32( log32(m) * RN_f32(1/0.301f) ) ), 0, 128)
// realized as bucket(m) = max{ k : T[k] <= m } via exact integer thresholds T
// and per-octave etab: bucket = base(clz) + 3 compares. DO NOT alter.
//
// R15: 2048 persistent blocks x 16 rows; ts columns register-cached; 32
// float4 stores/thread. (measured 272.1 us total)
// R16: (a) nontemporal stores — output stream (268.4 MB, write-once, never
// re-read) is 8.4x aggregate L2; plain stores allocate+dirty+evict every
// line. nt = no-allocate/early-evict. (b) hoist all 16 wave-uniform t_next
// scalar loads ahead of the row loop (SGPR prefetch, no per-4-row s_load
// stall). Bucket semantics unchanged.
// R17: fix compile — __builtin_nontemporal_store requires a clang
// ext_vector_type, not HIP_vector_type float4. Same layout (16B), same ISA
// addressing; only the C++ type changes.

#define NN 2048
#define BLOCK 256
#define ROWS 16
#define NTHR 130   // thresholds T[0..129]

typedef float f32x4 __attribute__((ext_vector_type(4)));

__global__ void build_thresholds_kernel(int* __restrict__ T) {
    const int k = blockIdx.x;              // 0..129
    __shared__ int s_min;
    if (threadIdx.x == 0) s_min = INT_MAX;
    __syncthreads();

    const float recip = (float)(1.0 / (double)0.301f);   // RN_f32(1/f32(0.301))
    const double est = exp(0.301 * (double)k);
    if (est > 2.0e9) {
        if (threadIdx.x == 0) T[k] = INT_MAX;
        return;
    }
    long long lo = (long long)floor(est) - 256;
    if (lo < 1) lo = 1;
    const long long m = lo + (long long)threadIdx.x;     // one candidate/thread
    const float lg = (float)log((double)m);              // CR f32 log of integer m
    const float q = lg * recip;                          // f32 RN multiply
    if ((int)q >= k) atomicMin(&s_min, (int)m);          // monotone predicate
    __syncthreads();
    if (threadIdx.x == 0) T[k] = s_min;
}

// etab[clz(m)] = (base, T[base+1], T[base+2], T[base+3]), base = bucket(2^(31-clz)).
__global__ void build_etab_kernel(const int* __restrict__ T, int4* __restrict__ etab) {
    const int c = threadIdx.x;             // clz value 0..31
    if (c >= 32) return;
    const long long mE = 1LL << (31 - c);
    int lo = 0, hi = NTHR - 1;             // base = max{k: T[k] <= 2^E}
    while (lo < hi) {
        const int mid = (lo + hi + 1) >> 1;
        if ((long long)T[mid] <= mE) lo = mid; else hi = mid - 1;
    }
    int4 e;
    e.x = lo;
    e.y = T[min(lo + 1, NTHR - 1)];
    e.z = T[min(lo + 2, NTHR - 1)];
    e.w = T[min(lo + 3, NTHR - 1)];
    etab[c] = e;
}

__device__ __forceinline__ float bias_elem(int t_next, int tj, int j, int i,
                                           const float* __restrict__ s_tsw,
                                           const int4* __restrict__ s_etab,
                                           float ts0, float pv) {
    if (j > i) return pv + ts0;            // non-causal: td=0 -> bucket 0
    int mi = t_next - tj;                  // >= 0 (rows sorted)
    mi = mi < 1 ? 1 : mi;                  // max(|td|, 1); mi in [1, 2^24)
    const int4 e = s_etab[__clz(mi)];      // mostly-broadcast LDS b128
    const int b = e.x + (mi >= e.y) + (mi >= e.z) + (mi >= e.w);
    return pv + s_tsw[b];
}

__global__ __launch_bounds__(BLOCK) void hstu_bias_kernel(
    const int* __restrict__ ts,       // [B, N] int32, sorted per row
    const float* __restrict__ ts_w,   // [129]
    const float* __restrict__ pos_w,  // [2N-1]
    const int4* __restrict__ etab,    // [32]
    float* __restrict__ out)          // [B, N, N]
{
    __shared__ float s_tsw[129];
    __shared__ int4 s_etab[32];
    const int tid = threadIdx.x;
    if (tid < 129) s_tsw[tid] = ts_w[tid];
    if (tid < 32) s_etab[tid] = etab[tid];

    const int grp = blockIdx.x;          // 0..2047
    const int b = grp >> 7;              // /128
    const int i0 = (grp & 127) << 4;     // *ROWS
    const int* __restrict__ ts_row = ts + b * NN;

    // ts columns are the same for all ROWS rows of this block: register-cache.
    const int j_0 = tid * 4;
    const int j_1 = tid * 4 + 1024;
    const int4 tj0 = *(const int4*)(ts_row + j_0);   // aligned 16B
    const int4 tj1 = *(const int4*)(ts_row + j_1);

    // R16(b): all 16 t_next values are wave-uniform & known now — prefetch
    // into SGPRs so no row of the store loop stalls on a dependent s_load.
    int tn[ROWS];
#pragma unroll
    for (int r = 0; r < ROWS; ++r) {
        const int i = i0 + r;
        tn[r] = ts_row[(i < NN - 1) ? (i + 1) : (NN - 1)];
    }

    __syncthreads();
    const float ts0 = s_tsw[0];
    float* __restrict__ out_base = out + (size_t)(b * NN + i0) * NN;

#pragma unroll
    for (int r = 0; r < ROWS; ++r) {
        const int i = i0 + r;
        const int t_next = tn[r];
        const float* __restrict__ pw = pos_w + (NN - 1 - i);           // pw[j]
        f32x4* __restrict__ out4 = (f32x4*)(out_base + (size_t)r * NN);

        float4 pva, pvb;                         // 4B-aligned 16B loads (L1-hit)
        __builtin_memcpy(&pva, pw + j_0, 16);
        __builtin_memcpy(&pvb, pw + j_1, 16);

        f32x4 ra, rb;
        ra.x = bias_elem(t_next, tj0.x, j_0 + 0, i, s_tsw, s_etab, ts0, pva.x);
        ra.y = bias_elem(t_next, tj0.y, j_0 + 1, i, s_tsw, s_etab, ts0, pva.y);
        ra.z = bias_elem(t_next, tj0.z, j_0 + 2, i, s_tsw, s_etab, ts0, pva.z);
        ra.w = bias_elem(t_next, tj0.w, j_0 + 3, i, s_tsw, s_etab, ts0, pva.w);
        rb.x = bias_elem(t_next, tj1.x, j_1 + 0, i, s_tsw, s_etab, ts0, pvb.x);
        rb.y = bias_elem(t_next, tj1.y, j_1 + 1, i, s_tsw, s_etab, ts0, pvb.y);
        rb.z = bias_elem(t_next, tj1.z, j_1 + 2, i, s_tsw, s_etab, ts0, pvb.z);
        rb.w = bias_elem(t_next, tj1.w, j_1 + 3, i, s_tsw, s_etab, ts0, pvb.w);

        // R16(a): streaming writes — no-allocate / early-evict in L2.
        __builtin_nontemporal_store(ra, out4 + tid);
        __builtin_nontemporal_store(rb, out4 + tid + 256);
    }
}

extern "C" void kernel_launch(void* const* d_in, const int* in_sizes, int n_in,
                              void* d_out, int out_size, void* d_ws, size_t ws_size,
                              hipStream_t stream) {
    const int* ts = (const int*)d_in[0];        // all_timestamps [16,2048]
    const float* ts_w = (const float*)d_in[1];  // [129]
    const float* pos_w = (const float*)d_in[2]; // [4095]
    float* out = (float*)d_out;                 // [16,2048,2048] f32
    int* T = (int*)d_ws;                        // [130] at ws+0
    int4* etab = (int4*)((char*)d_ws + 1024);   // [32] at ws+1024 (16B aligned)

    build_thresholds_kernel<<<dim3(NTHR), dim3(512), 0, stream>>>(T);
    build_etab_kernel<<<dim3(1), dim3(32), 0, stream>>>(T, etab);

    const int B = 16;
    hstu_bias_kernel<<<dim3(B * NN / ROWS), dim3(BLOCK), 0, stream>>>(ts, ts_w, pos_w, etab, out);
}

// Round 3
// 273.251 us; speedup vs baseline: 1.0360x; 1.0360x over previous
//
#include <hip/hip_runtime.h>
#include <math.h>
#include <limits.h>

// RelativeBucketedTimeAndPositionBasedBias — B=16, N=2048, NUM_BUCKETS=128
// out[b,i,j] = pos_w[N-1 + j - i] + ts_w[bucket(b,i,j)]
//   diff = ext[b,i+1] - ext[b,j]; m = max(|diff·causal|, 1)  (integer, < 2^24)
//
// VERIFIED BIT-EXACT (R12-R14, absmax=0): ref pipeline is
//   bucket = clip(trunc( RN_f32( log32(m) * RN_f32(1/0.301f) ) ), 0, 128)
// realized as bucket(m) = max{ k : T[k] <= m } via exact integer thresholds T
// and per-octave etab: bucket = base(clz) + 3 compares. DO NOT alter.
//
// R15: 2048 persistent blocks x 16 rows; ts columns register-cached; 32
// float4 stores/thread. (272.1 us total)
// R16/R17: nt stores + t_next SGPR prefetch + full unroll -> 283.1 us (+11,
// regression; reverted).
// R18: profile decomposition — top-5 dispatches are ALL 1-GiB workspace
// poison fills (~170 us @ 6.3 TB/s write). Timed region = ws-fill + our
// kernels. We use 1.5 KB of d_ws. Eliminate d_ws entirely: build etab
// per-block in LDS inside the main kernel. Same verified predicate
// q(m) = (int)( (float)log((double)m) * recip ) (monotone in m), thresholds
// found by per-octave binary search => identical T values, bit-exact.
// Also removes 2 setup launches. Main loop = exact R15 form.

#define NN 2048
#define BLOCK 256
#define ROWS 16

__device__ __forceinline__ int qbucket(long long m, float recip) {
    const float lg = (float)log((double)m);   // CR f32 log of integer m (f64 path)
    return (int)(lg * recip);                 // f32 RN multiply, trunc
}

__device__ __forceinline__ float bias_elem(int t_next, int tj, int j, int i,
                                           const float* __restrict__ s_tsw,
                                           const int4* __restrict__ s_etab,
                                           float ts0, float pv) {
    if (j > i) return pv + ts0;            // non-causal: td=0 -> bucket 0
    int mi = t_next - tj;                  // >= 0 (rows sorted)
    mi = mi < 1 ? 1 : mi;                  // max(|td|, 1); mi in [1, 2^24)
    const int4 e = s_etab[__clz(mi)];      // mostly-broadcast LDS b128
    const int b = e.x + (mi >= e.y) + (mi >= e.z) + (mi >= e.w);
    return pv + s_tsw[b];
}

__global__ __launch_bounds__(BLOCK) void hstu_bias_kernel(
    const int* __restrict__ ts,       // [B, N] int32, sorted per row
    const float* __restrict__ ts_w,   // [129]
    const float* __restrict__ pos_w,  // [2N-1]
    float* __restrict__ out)          // [B, N, N]
{
    __shared__ float s_tsw[129];
    __shared__ int4 s_etab[32];
    const int tid = threadIdx.x;
    if (tid < 129) s_tsw[tid] = ts_w[tid];

    // ---- R18 in-block etab build (replaces ws + 2 setup kernels) ----
    // etab[c] = (base, T[base+1], T[base+2], T[base+3]) for octave E = 31-c,
    // base = q(2^E) = max{k : T[k] <= 2^E}. T[k] = min{m : q(m) >= k} found by
    // binary search within the octave (q monotone non-decreasing); if the
    // threshold lies beyond the octave, INT_MAX (compare never fires for mi
    // in this octave since mi < 2^(E+1) <= T). Octave spans 2.303 buckets ->
    // at most 3 boundaries: 3 slots suffice (same invariant as R12-R14).
    const float recip = (float)(1.0 / (double)0.301f);   // RN_f32(1/f32(0.301))
    int* e_flat = (int*)s_etab;
    if (tid < 32) {
        const long long mE = 1LL << (31 - tid);
        e_flat[tid * 4 + 0] = qbucket(mE, recip);        // base
    } else if (tid < 128) {
        const int idx = tid - 32;
        const int c = idx / 3;             // octave's clz value 0..31
        const int s = idx % 3;             // slot 0..2 -> e.y/e.z/e.w
        const long long mE = 1LL << (31 - c);
        const long long hi0 = mE + mE - 1;
        const int k = qbucket(mE, recip) + s + 1;        // target bucket
        int t = INT_MAX;
        if (k <= 129 && qbucket(hi0, recip) >= k) {
            long long lo = mE, hi = hi0;
            while (lo < hi) {              // min m in octave with q(m) >= k
                const long long mid = (lo + hi) >> 1;
                if (qbucket(mid, recip) >= k) hi = mid; else lo = mid + 1;
            }
            t = (lo > (long long)INT_MAX) ? INT_MAX : (int)lo;
        }
        e_flat[c * 4 + 1 + s] = t;
    }

    const int grp = blockIdx.x;          // 0..2047
    const int b = grp >> 7;              // /128
    const int i0 = (grp & 127) << 4;     // *ROWS
    const int* __restrict__ ts_row = ts + b * NN;

    // ts columns are the same for all ROWS rows of this block: register-cache.
    const int j_0 = tid * 4;
    const int j_1 = tid * 4 + 1024;
    const int4 tj0 = *(const int4*)(ts_row + j_0);   // aligned 16B
    const int4 tj1 = *(const int4*)(ts_row + j_1);

    __syncthreads();
    const float ts0 = s_tsw[0];
    float* __restrict__ out_base = out + (size_t)(b * NN + i0) * NN;

#pragma unroll 4
    for (int r = 0; r < ROWS; ++r) {
        const int i = i0 + r;
        const int t_next = ts_row[(i < NN - 1) ? (i + 1) : (NN - 1)];  // uniform s_load
        const float* __restrict__ pw = pos_w + (NN - 1 - i);           // pw[j]
        float4* __restrict__ out4 = (float4*)(out_base + (size_t)r * NN);

        float4 pva, pvb;                         // 4B-aligned 16B loads (L1-hit)
        __builtin_memcpy(&pva, pw + j_0, 16);
        __builtin_memcpy(&pvb, pw + j_1, 16);

        float4 ra, rb;
        ra.x = bias_elem(t_next, tj0.x, j_0 + 0, i, s_tsw, s_etab, ts0, pva.x);
        ra.y = bias_elem(t_next, tj0.y, j_0 + 1, i, s_tsw, s_etab, ts0, pva.y);
        ra.z = bias_elem(t_next, tj0.z, j_0 + 2, i, s_tsw, s_etab, ts0, pva.z);
        ra.w = bias_elem(t_next, tj0.w, j_0 + 3, i, s_tsw, s_etab, ts0, pva.w);
        rb.x = bias_elem(t_next, tj1.x, j_1 + 0, i, s_tsw, s_etab, ts0, pvb.x);
        rb.y = bias_elem(t_next, tj1.y, j_1 + 1, i, s_tsw, s_etab, ts0, pvb.y);
        rb.z = bias_elem(t_next, tj1.z, j_1 + 2, i, s_tsw, s_etab, ts0, pvb.z);
        rb.w = bias_elem(t_next, tj1.w, j_1 + 3, i, s_tsw, s_etab, ts0, pvb.w);

        out4[tid] = ra;
        out4[tid + 256] = rb;
    }
}

extern "C" void kernel_launch(void* const* d_in, const int* in_sizes, int n_in,
                              void* d_out, int out_size, void* d_ws, size_t ws_size,
                              hipStream_t stream) {
    const int* ts = (const int*)d_in[0];        // all_timestamps [16,2048]
    const float* ts_w = (const float*)d_in[1];  // [129]
    const float* pos_w = (const float*)d_in[2]; // [4095]
    float* out = (float*)d_out;                 // [16,2048,2048] f32
    (void)d_ws; (void)ws_size;                  // R18: workspace unused

    const int B = 16;
    hstu_bias_kernel<<<dim3(B * NN / ROWS), dim3(BLOCK), 0, stream>>>(ts, ts_w, pos_w, out);
}

// Round 4
// 271.318 us; speedup vs baseline: 1.0434x; 1.0071x over previous
//
#include <hip/hip_runtime.h>
#include <math.h>
#include <limits.h>

// RelativeBucketedTimeAndPositionBasedBias — B=16, N=2048, NUM_BUCKETS=128
// out[b,i,j] = pos_w[N-1 + j - i] + ts_w[bucket(b,i,j)]
//   diff = ext[b,i+1] - ext[b,j]; m = max(|diff·causal|, 1)  (integer, < 2^24)
//
// VERIFIED BIT-EXACT (R12-R14, absmax=0): ref pipeline is
//   bucket = clip(trunc( RN_f32( log32(m) * RN_f32(1/0.301f) ) ), 0, 128)
// realized as bucket(m) = max{ k : T[k] <= m } via exact integer thresholds T.
// DO NOT alter the predicate q(m) = (int)((float)log((double)m) * recip).
//
// R15: 2048 blocks x 16 rows, reg-cached ts columns. 272.1 us.
// R16/17: nt-store bundle +11 us (reverted). R18: ws-free in-block etab:
// 273.2 us AND fills persist -> 1-GiB poison fill (~163 us @6.6 TB/s) is
// UNCONDITIONAL. Timed = fill + main(~95-105) + gaps. d_ws is free; in-block
// f64-log build was pure overhead. Fills also prove plain streaming stores
// reach 6.6 TB/s -> main's gap to the ~43 us write floor is latency:
// per-element two-hop dependent LDS chain (etab b128 -> b -> s_tsw[b] gather).
// R19: single-hop lookup. etabT[c]={T[base+1..3]}, etabW[c]={ts_w[base..base+3]}.
// Element: clz -> two INDEPENDENT b128 reads @ c -> 3 cndmask selects.
// T non-decreasing => highest-threshold-satisfied == base+sum(mi>=T_s): same
// bucket, same weight, zero arithmetic change -> bit-exact. Causal check
// dropped: j>i => mi<=0 => clamp 1 => clz 31 => base 0 => w.x=ts_w[0], which
// IS the non-causal value. s_tsw stage deleted.

#define NN 2048
#define BLOCK 256
#define ROWS 16
#define NTHR 130   // thresholds T[0..129]

__global__ void build_thresholds_kernel(int* __restrict__ T) {
    const int k = blockIdx.x;              // 0..129
    __shared__ int s_min;
    if (threadIdx.x == 0) s_min = INT_MAX;
    __syncthreads();

    const float recip = (float)(1.0 / (double)0.301f);   // RN_f32(1/f32(0.301))
    const double est = exp(0.301 * (double)k);
    if (est > 2.0e9) {
        if (threadIdx.x == 0) T[k] = INT_MAX;
        return;
    }
    long long lo = (long long)floor(est) - 256;
    if (lo < 1) lo = 1;
    const long long m = lo + (long long)threadIdx.x;     // one candidate/thread
    const float lg = (float)log((double)m);              // CR f32 log of integer m
    const float q = lg * recip;                          // f32 RN multiply
    if ((int)q >= k) atomicMin(&s_min, (int)m);          // monotone predicate
    __syncthreads();
    if (threadIdx.x == 0) T[k] = s_min;
}

// Per-octave tables. base = max{k: T[k] <= 2^E}, E = 31-c.
// etabT[c] = (T[base+1], T[base+2], T[base+3], 0)      — select thresholds
// etabW[c] = (ts_w[base], ..., ts_w[base+3])           — the 4 reachable weights
// Octave spans ln(2)/0.301 = 2.303 buckets -> <=3 boundaries: 3 slots suffice
// (same invariant verified in R12-R14).
__global__ void build_etab_kernel(const int* __restrict__ T,
                                  const float* __restrict__ ts_w,
                                  int4* __restrict__ etabT,
                                  float4* __restrict__ etabW) {
    const int c = threadIdx.x;             // clz value 0..31
    if (c >= 32) return;
    const long long mE = 1LL << (31 - c);
    int lo = 0, hi = NTHR - 1;             // base = max{k: T[k] <= 2^E}
    while (lo < hi) {
        const int mid = (lo + hi + 1) >> 1;
        if ((long long)T[mid] <= mE) lo = mid; else hi = mid - 1;
    }
    int4 t;
    t.x = T[min(lo + 1, NTHR - 1)];
    t.y = T[min(lo + 2, NTHR - 1)];
    t.z = T[min(lo + 3, NTHR - 1)];
    t.w = 0;
    etabT[c] = t;
    float4 w;
    w.x = ts_w[min(lo + 0, 128)];
    w.y = ts_w[min(lo + 1, 128)];
    w.z = ts_w[min(lo + 2, 128)];
    w.w = ts_w[min(lo + 3, 128)];
    etabW[c] = w;
}

__device__ __forceinline__ float bias_elem(int t_next, int tj,
                                           const int4* __restrict__ sT,
                                           const float4* __restrict__ sW,
                                           float pv) {
    int mi = t_next - tj;                  // j<=i: >=0 (sorted); j>i: <=0
    mi = mi < 1 ? 1 : mi;                  // max(|td·causal|,1); j>i lands at 1
    const int c = __clz(mi);
    const int4 t = sT[c];                  // independent broadcast b128
    const float4 w = sW[c];                // independent broadcast b128
    // T non-decreasing within octave: pick weight of highest satisfied slot
    // == ts_w[base + (mi>=t.x)+(mi>=t.y)+(mi>=t.z)] (verified realization).
    float r = w.x;
    r = (mi >= t.x) ? w.y : r;
    r = (mi >= t.y) ? w.z : r;
    r = (mi >= t.z) ? w.w : r;
    return pv + r;
}

__global__ __launch_bounds__(BLOCK) void hstu_bias_kernel(
    const int* __restrict__ ts,       // [B, N] int32, sorted per row
    const float* __restrict__ pos_w,  // [2N-1]
    const int4* __restrict__ etabT,   // [32]
    const float4* __restrict__ etabW, // [32]
    float* __restrict__ out)          // [B, N, N]
{
    __shared__ int4 s_etabT[32];
    __shared__ float4 s_etabW[32];
    const int tid = threadIdx.x;
    if (tid < 32) {
        s_etabT[tid] = etabT[tid];
        s_etabW[tid] = etabW[tid];
    }

    const int grp = blockIdx.x;          // 0..2047
    const int b = grp >> 7;              // /128
    const int i0 = (grp & 127) << 4;     // *ROWS
    const int* __restrict__ ts_row = ts + b * NN;

    // ts columns are the same for all ROWS rows of this block: register-cache.
    const int j_0 = tid * 4;
    const int j_1 = tid * 4 + 1024;
    const int4 tj0 = *(const int4*)(ts_row + j_0);   // aligned 16B
    const int4 tj1 = *(const int4*)(ts_row + j_1);

    __syncthreads();
    float* __restrict__ out_base = out + (size_t)(b * NN + i0) * NN;

#pragma unroll 4
    for (int r = 0; r < ROWS; ++r) {
        const int i = i0 + r;
        const int t_next = ts_row[(i < NN - 1) ? (i + 1) : (NN - 1)];  // uniform s_load
        const float* __restrict__ pw = pos_w + (NN - 1 - i);           // pw[j]
        float4* __restrict__ out4 = (float4*)(out_base + (size_t)r * NN);

        float4 pva, pvb;                         // 4B-aligned 16B loads (L1-hit)
        __builtin_memcpy(&pva, pw + j_0, 16);
        __builtin_memcpy(&pvb, pw + j_1, 16);

        float4 ra, rb;
        ra.x = bias_elem(t_next, tj0.x, s_etabT, s_etabW, pva.x);
        ra.y = bias_elem(t_next, tj0.y, s_etabT, s_etabW, pva.y);
        ra.z = bias_elem(t_next, tj0.z, s_etabT, s_etabW, pva.z);
        ra.w = bias_elem(t_next, tj0.w, s_etabT, s_etabW, pva.w);
        rb.x = bias_elem(t_next, tj1.x, s_etabT, s_etabW, pvb.x);
        rb.y = bias_elem(t_next, tj1.y, s_etabT, s_etabW, pvb.y);
        rb.z = bias_elem(t_next, tj1.z, s_etabT, s_etabW, pvb.z);
        rb.w = bias_elem(t_next, tj1.w, s_etabT, s_etabW, pvb.w);

        out4[tid] = ra;
        out4[tid + 256] = rb;
    }
}

extern "C" void kernel_launch(void* const* d_in, const int* in_sizes, int n_in,
                              void* d_out, int out_size, void* d_ws, size_t ws_size,
                              hipStream_t stream) {
    const int* ts = (const int*)d_in[0];        // all_timestamps [16,2048]
    const float* ts_w = (const float*)d_in[1];  // [129]
    const float* pos_w = (const float*)d_in[2]; // [4095]
    float* out = (float*)d_out;                 // [16,2048,2048] f32
    int* T = (int*)d_ws;                        // [130] at ws+0
    int4* etabT = (int4*)((char*)d_ws + 1024);  // [32] at ws+1024 (16B aligned)
    float4* etabW = (float4*)((char*)d_ws + 1536); // [32] at ws+1536

    build_thresholds_kernel<<<dim3(NTHR), dim3(512), 0, stream>>>(T);
    build_etab_kernel<<<dim3(1), dim3(64), 0, stream>>>(T, ts_w, etabT, etabW);

    const int B = 16;
    hstu_bias_kernel<<<dim3(B * NN / ROWS), dim3(BLOCK), 0, stream>>>(ts, pos_w, etabT, etabW, out);
}

// Round 5
// 270.609 us; speedup vs baseline: 1.0461x; 1.0026x over previous
//
#include <hip/hip_runtime.h>
#include <math.h>
#include <limits.h>

// RelativeBucketedTimeAndPositionBasedBias — B=16, N=2048, NUM_BUCKETS=128
// out[b,i,j] = pos_w[N-1 + j - i] + ts_w[bucket(b,i,j)]
//   diff = ext[b,i+1] - ext[b,j]; m = max(|diff·causal|, 1)  (integer, < 2^24)
//
// VERIFIED BIT-EXACT (R12-R14, absmax=0): ref pipeline is
//   bucket = clip(trunc( RN_f32( log32(m) * RN_f32(1/0.301f) ) ), 0, 128)
// realized as bucket(m) = max{ k : T[k] <= m } via exact integer thresholds T.
// DO NOT alter the predicate q(m) = (int)((float)log((double)m) * recip).
//
// Session ledger:
//  R15 272.1 | R16/17 nt-store bundle 283.1 (reverted) | R18 ws-free 273.2
//  R19 single-hop etabT/etabW + causal-drop 271.3.
// Decomposition (R18/R19 profiles): 1-GiB ws poison fill ~163 us
// (UNCONDITIONAL — persists with ws unused; runs at 6.6 TB/s ceiling)
// + out poison ~42 us + main ~50 us (store-bound: insensitive to +/- large
// compute changes, R18/R19) + setup/gaps ~10-15 us.
// R20: shave the controllable slack. (a) ONE merged setup kernel (1 block,
// 128 thr): per-octave binary-search threshold build — exact logic HW-verified
// bit-exact in R18; direct-weight etabW transform HW-verified in R19.
// (b) hoist 16 wave-uniform t_next scalar loads (isolated; SGPR prefetch).
// Main loop otherwise R19-identical.

#define NN 2048
#define BLOCK 256
#define ROWS 16

__device__ __forceinline__ int qbucket(long long m, float recip) {
    const float lg = (float)log((double)m);   // CR f32 log of integer m (f64 path)
    return (int)(lg * recip);                 // f32 RN multiply, trunc
}

// Merged setup: etabT[c] = (T[base+1], T[base+2], T[base+3], 0),
//               etabW[c] = (ts_w[base..base+3]),  base = q(2^E), E = 31-c.
// T[k] = min{m : q(m) >= k} searched within the octave (q monotone);
// INT_MAX if the boundary lies beyond the octave (compare never fires since
// mi < 2^(E+1) <= T). Octave spans ln(2)/0.301 = 2.303 buckets -> <=3
// boundaries: 3 slots suffice (R12-R14 invariant; R18 verified this build).
__global__ void build_etab_kernel(const float* __restrict__ ts_w,
                                  int4* __restrict__ etabT,
                                  float4* __restrict__ etabW) {
    const int tid = threadIdx.x;           // 0..127
    if (tid >= 128) return;
    const int c = tid >> 2;                // octave's clz value 0..31
    const int s = tid & 3;                 // slot
    const float recip = (float)(1.0 / (double)0.301f);   // RN_f32(1/f32(0.301))
    const long long mE = 1LL << (31 - c);
    const int base = qbucket(mE, recip);

    // weight slot: etabW[c][s] = ts_w[min(base+s, 128)]
    ((float*)etabW)[c * 4 + s] = ts_w[min(base + s, 128)];

    // threshold slots: s=1..3 -> etabT[c][s-1] = T[base+s]; s=0 -> pad 0
    int* tflat = (int*)etabT;
    if (s == 0) {
        tflat[c * 4 + 3] = 0;
    } else {
        const long long hi0 = mE + mE - 1;
        const int k = base + s;            // target bucket boundary
        int t = INT_MAX;
        if (k <= 129 && qbucket(hi0, recip) >= k) {
            long long lo = mE, hi = hi0;
            while (lo < hi) {              // min m in octave with q(m) >= k
                const long long mid = (lo + hi) >> 1;
                if (qbucket(mid, recip) >= k) hi = mid; else lo = mid + 1;
            }
            t = (lo > (long long)INT_MAX) ? INT_MAX : (int)lo;
        }
        tflat[c * 4 + (s - 1)] = t;
    }
}

__device__ __forceinline__ float bias_elem(int t_next, int tj,
                                           const int4* __restrict__ sT,
                                           const float4* __restrict__ sW,
                                           float pv) {
    int mi = t_next - tj;                  // j<=i: >=0 (sorted); j>i: <=0
    mi = mi < 1 ? 1 : mi;                  // max(|td·causal|,1); j>i lands at 1
    const int c = __clz(mi);
    const int4 t = sT[c];                  // independent broadcast b128
    const float4 w = sW[c];                // independent broadcast b128
    // T non-decreasing within octave: weight of highest satisfied slot
    // == ts_w[base + (mi>=t.x)+(mi>=t.y)+(mi>=t.z)] (verified realization).
    float r = w.x;
    r = (mi >= t.x) ? w.y : r;
    r = (mi >= t.y) ? w.z : r;
    r = (mi >= t.z) ? w.w : r;
    return pv + r;
}

__global__ __launch_bounds__(BLOCK) void hstu_bias_kernel(
    const int* __restrict__ ts,       // [B, N] int32, sorted per row
    const float* __restrict__ pos_w,  // [2N-1]
    const int4* __restrict__ etabT,   // [32]
    const float4* __restrict__ etabW, // [32]
    float* __restrict__ out)          // [B, N, N]
{
    __shared__ int4 s_etabT[32];
    __shared__ float4 s_etabW[32];
    const int tid = threadIdx.x;
    if (tid < 32) {
        s_etabT[tid] = etabT[tid];
        s_etabW[tid] = etabW[tid];
    }

    const int grp = blockIdx.x;          // 0..2047
    const int b = grp >> 7;              // /128
    const int i0 = (grp & 127) << 4;     // *ROWS
    const int* __restrict__ ts_row = ts + b * NN;

    // ts columns are the same for all ROWS rows of this block: register-cache.
    const int j_0 = tid * 4;
    const int j_1 = tid * 4 + 1024;
    const int4 tj0 = *(const int4*)(ts_row + j_0);   // aligned 16B
    const int4 tj1 = *(const int4*)(ts_row + j_1);

    // R20(b): all 16 t_next values are wave-uniform & known now — prefetch
    // (scalar loads pipeline back-to-back instead of serializing per row).
    int tn[ROWS];
#pragma unroll
    for (int r = 0; r < ROWS; ++r) {
        const int i = i0 + r;
        tn[r] = ts_row[(i < NN - 1) ? (i + 1) : (NN - 1)];
    }

    __syncthreads();
    float* __restrict__ out_base = out + (size_t)(b * NN + i0) * NN;

#pragma unroll 4
    for (int r = 0; r < ROWS; ++r) {
        const int i = i0 + r;
        const int t_next = tn[r];
        const float* __restrict__ pw = pos_w + (NN - 1 - i);           // pw[j]
        float4* __restrict__ out4 = (float4*)(out_base + (size_t)r * NN);

        float4 pva, pvb;                         // 4B-aligned 16B loads (L1-hit)
        __builtin_memcpy(&pva, pw + j_0, 16);
        __builtin_memcpy(&pvb, pw + j_1, 16);

        float4 ra, rb;
        ra.x = bias_elem(t_next, tj0.x, s_etabT, s_etabW, pva.x);
        ra.y = bias_elem(t_next, tj0.y, s_etabT, s_etabW, pva.y);
        ra.z = bias_elem(t_next, tj0.z, s_etabT, s_etabW, pva.z);
        ra.w = bias_elem(t_next, tj0.w, s_etabT, s_etabW, pva.w);
        rb.x = bias_elem(t_next, tj1.x, s_etabT, s_etabW, pvb.x);
        rb.y = bias_elem(t_next, tj1.y, s_etabT, s_etabW, pvb.y);
        rb.z = bias_elem(t_next, tj1.z, s_etabT, s_etabW, pvb.z);
        rb.w = bias_elem(t_next, tj1.w, s_etabT, s_etabW, pvb.w);

        out4[tid] = ra;
        out4[tid + 256] = rb;
    }
}

extern "C" void kernel_launch(void* const* d_in, const int* in_sizes, int n_in,
                              void* d_out, int out_size, void* d_ws, size_t ws_size,
                              hipStream_t stream) {
    const int* ts = (const int*)d_in[0];        // all_timestamps [16,2048]
    const float* ts_w = (const float*)d_in[1];  // [129]
    const float* pos_w = (const float*)d_in[2]; // [4095]
    float* out = (float*)d_out;                 // [16,2048,2048] f32
    int4* etabT = (int4*)d_ws;                  // [32] at ws+0   (16B aligned)
    float4* etabW = (float4*)((char*)d_ws + 512); // [32] at ws+512

    build_etab_kernel<<<dim3(1), dim3(128), 0, stream>>>(ts_w, etabT, etabW);

    const int B = 16;
    hstu_bias_kernel<<<dim3(B * NN / ROWS), dim3(BLOCK), 0, stream>>>(ts, pos_w, etabT, etabW, out);
}